// Round 11
// baseline (278.996 us; speedup 1.0000x reference)
//
#include <hip/hip_runtime.h>
#include <math.h>

#define N_NODES 100000
#define N_EDGES 1600000
#define IN_F 64
#define OUT_F 64
#define KK 4
#define KY 320               // 256 (k*64+i) + 64 (x concat for root_w)
#define EPS 1e-15f
#define NBUCK 391            // ceil(100000/256) coarse buckets (dst>>8)
#define CHUNK 4096           // edges per binA1 block
#define BSTRIDE 5120         // padded bucket region stride (mean 4092, sigma 64)

typedef __attribute__((ext_vector_type(8))) short short8;    // 8 x bf16 (4 VGPRs)
typedef __attribute__((ext_vector_type(4))) float float4v;   // MFMA acc

// ---- module-global scratch ----
__device__ int            g_bcur[NBUCK];                     // bucket cursors / final counts
__device__ int            g_bbase[NBUCK];                    // bucket global CSR base
__device__ unsigned int   g_binned[NBUCK * BSTRIDE];         // (src<<8)|dst_local, bucket-major, 8 MB
__device__ int            g_off[N_NODES + 1];                // final CSR offsets
__device__ float          g_isd[N_NODES];
__device__ float          g_w2[KK * 2];                      // -0.5/(eps+sigma^2)
__device__ unsigned short g_xp[(size_t)N_NODES * IN_F];      // bf16 x, 12.8 MB (gather operand)
__device__ int            g_srcs[N_EDGES];                   // src per edge, dst-CSR order
__device__ unsigned short g_gt[OUT_F * KY];                  // G'^T [o][kk] bf16, 40 KB

static __device__ __forceinline__ unsigned short f2bf(float f) {
    unsigned int u = __float_as_uint(f);
    unsigned int r = u + 0x7fffu + ((u >> 16) & 1u);   // RNE
    return (unsigned short)(r >> 16);
}
static __device__ __forceinline__ float bflo(unsigned int u) { return __uint_as_float(u << 16); }
static __device__ __forceinline__ float bfhi(unsigned int u) { return __uint_as_float(u & 0xffff0000u); }
static __device__ __forceinline__ unsigned int pk(float a, float b) {
    return (unsigned int)f2bf(a) | ((unsigned int)f2bf(b) << 16);
}

// ---------------- K1: prep = zero(bcur) + xpack + packg ----------------
__global__ void prep_kernel(const float* __restrict__ x, const float* __restrict__ g,
                            const float* __restrict__ rw) {
    int t = blockIdx.x * blockDim.x + threadIdx.x;
    if (t < N_NODES * (IN_F / 2)) {                  // xpack: bf16 pairs
        float a = x[2 * t], b = x[2 * t + 1];
        ((unsigned int*)g_xp)[t] = pk(a, b);
    }
    if (t < NBUCK) g_bcur[t] = 0;
    if (t < OUT_F * KY) {                            // packg
        int o = t / KY, kk = t % KY;
        float v;
        if (kk < 256) {
            int k = kk >> 6, i = kk & 63;
            v = g[i * 256 + k * 64 + o];
        } else {
            v = rw[(kk - 256) * 64 + o];
        }
        g_gt[o * KY + kk] = f2bf(v);
    }
}

// ---------------- K2: binA1 — LDS-grouped coarse bucket sort ----------------
__global__ __launch_bounds__(256, 5) void binA1_kernel(const int* __restrict__ src,
                                                       const int* __restrict__ dst) {
    __shared__ unsigned int   s_ent[CHUNK];          // 16 KB entries, bucket-grouped
    __shared__ unsigned short s_bkt[CHUNK];          // 8 KB bucket id per slot
    __shared__ int s_hist[NBUCK];
    __shared__ int s_off[448];                       // exclusive scan (7*64 >= NBUCK)
    __shared__ int s_gbase[NBUCK];
    __shared__ int s_cur[NBUCK];
    int t = threadIdx.x;
    int e0 = blockIdx.x * CHUNK;
    int nvalid = N_EDGES - e0; if (nvalid > CHUNK) nvalid = CHUNK;

    int myb[16];
    unsigned int mye[16];
#pragma unroll
    for (int r = 0; r < 16; ++r) {
        int e = e0 + r * 256 + t;
        if (e < N_EDGES) {
            int s = src[e], d = dst[e];
            myb[r] = d >> 8;
            mye[r] = ((unsigned int)s << 8) | (unsigned int)(d & 255);
        } else myb[r] = -1;
    }
    for (int i = t; i < NBUCK; i += 256) { s_hist[i] = 0; s_cur[i] = 0; }
    __syncthreads();
#pragma unroll
    for (int r = 0; r < 16; ++r)
        if (myb[r] >= 0) atomicAdd(&s_hist[myb[r]], 1);
    __syncthreads();
    // exclusive scan of s_hist -> s_off (wave 0, shuffle-scan with carry)
    if (t < 64) {
        int carry = 0;
        for (int seg = 0; seg < 7; ++seg) {
            int idx = seg * 64 + t;
            int v = (idx < NBUCK) ? s_hist[idx] : 0;
            int orig = v;
#pragma unroll
            for (int d = 1; d < 64; d <<= 1) {
                int u = __shfl_up(v, d);
                if (t >= d) v += u;
            }
            s_off[idx] = carry + v - orig;
            carry += __shfl(v, 63);
        }
    }
    __syncthreads();
    // reserve global runs
    for (int i = t; i < NBUCK; i += 256) {
        int c = s_hist[i];
        s_gbase[i] = (c > 0) ? atomicAdd(&g_bcur[i], c) : 0;
    }
    __syncthreads();
    // place into LDS, bucket-grouped
#pragma unroll
    for (int r = 0; r < 16; ++r) {
        int b = myb[r];
        if (b >= 0) {
            int slot = s_off[b] + atomicAdd(&s_cur[b], 1);
            s_ent[slot] = mye[r];
            s_bkt[slot] = (unsigned short)b;
        }
    }
    __syncthreads();
    // flush coalesced runs
    for (int slot = t; slot < nvalid; slot += 256) {
        int b = s_bkt[slot];
        int pos = b * BSTRIDE + s_gbase[b] + (slot - s_off[b]);
        g_binned[pos] = s_ent[slot];
    }
}

// ---------------- K3: scan bucket counts -> bucket CSR bases; + w2 ----------------
__global__ void bscan_kernel(const float* __restrict__ sigma) {
    __shared__ int sh[512];
    int t = threadIdx.x;
    if (t < KK * 2) {
        float s = sigma[t];
        g_w2[t] = -0.5f / (EPS + s * s);
    }
    int v = (t < NBUCK) ? g_bcur[t] : 0;
    sh[t] = v;
    __syncthreads();
#pragma unroll
    for (int d = 1; d < 512; d <<= 1) {
        int u = (t >= d) ? sh[t - d] : 0;
        __syncthreads();
        sh[t] += u;
        __syncthreads();
    }
    if (t < NBUCK) g_bbase[t] = sh[t] - v;
}

// ---------------- K4: binA2 — per-bucket counting sort to exact CSR + g_off + isd ----------------
__global__ __launch_bounds__(256, 8) void binA2_kernel() {
    __shared__ int s_hist[256], s_off[256], s_cur[256];
    int b = blockIdx.x;
    int t = threadIdx.x;
    int cnt = g_bcur[b];
    int gbase = g_bbase[b];
    int n0 = b * 256;
    const unsigned int* ent = g_binned + (size_t)b * BSTRIDE;
    s_hist[t] = 0; s_cur[t] = 0;
    __syncthreads();
    for (int i = t; i < cnt; i += 256) atomicAdd(&s_hist[ent[i] & 255u], 1);
    __syncthreads();
    // exclusive scan over 256 (wave 0)
    if (t < 64) {
        int carry = 0;
        for (int seg = 0; seg < 4; ++seg) {
            int idx = seg * 64 + t;
            int v = s_hist[idx];
            int orig = v;
#pragma unroll
            for (int d = 1; d < 64; d <<= 1) {
                int u = __shfl_up(v, d);
                if (t >= d) v += u;
            }
            s_off[idx] = carry + v - orig;
            carry += __shfl(v, 63);
        }
    }
    __syncthreads();
    int n = n0 + t;
    if (n < N_NODES) {
        g_off[n] = gbase + s_off[t];
        int c = s_hist[t];
        g_isd[n] = (c > 0) ? rsqrtf((float)c) : 0.0f;
    }
    if (b == NBUCK - 1 && t == 0) g_off[N_NODES] = N_EDGES;
    __syncthreads();
    for (int i = t; i < cnt; i += 256) {
        unsigned int e = ent[i];
        int dl = e & 255u;
        int pos = gbase + s_off[dl] + atomicAdd(&s_cur[dl], 1);
        g_srcs[pos] = (int)(e >> 8);
    }
}

// ---------------- K5: fused aggregate (w recomputed on the fly) + MFMA epilogue ----------------
// launch_bounds (256,6): R10 ran at Occupancy=35% (bounds-capped 4 blocks/CU) and was
// latency-bound at 2.9 TB/s; LDS (21KB) allows 7 blocks, VGPR 64 allows 8 -> cap was binding.
__global__ __launch_bounds__(256, 6) void fused_kernel(const float* __restrict__ mu,
                                                       const float* __restrict__ bias,
                                                       float* __restrict__ out) {
    __shared__ unsigned short yt[32][328];
    int t = threadIdx.x;
    int wv = t >> 6, L = t & 63;
    int grp = L >> 3, c = L & 7;
    int n0 = blockIdx.x * 32;
    int n = n0 + wv * 8 + grp;

    int off = g_off[n], end = g_off[n + 1];
    int cdeg = end - off;
    float mu0[KK], w20[KK], t1[KK];
    {
        float a1 = (cdeg > 0) ? rsqrtf((float)cdeg) : 0.0f;
#pragma unroll
        for (int k = 0; k < KK; ++k) {
            mu0[k] = mu[k * 2 + 0];
            w20[k] = g_w2[k * 2 + 0];
            float d1 = a1 - mu[k * 2 + 1];
            t1[k] = g_w2[k * 2 + 1] * d1 * d1;
        }
    }

    float y[KK][8];
#pragma unroll
    for (int k = 0; k < KK; ++k)
#pragma unroll
        for (int i = 0; i < 8; ++i) y[k][i] = 0.0f;

    int j = off;
    for (; j + 3 < end; j += 4) {            // 4 edges in flight
        int s0 = g_srcs[j], s1 = g_srcs[j + 1], s2 = g_srcs[j + 2], s3 = g_srcs[j + 3];
        float a0 = g_isd[s0], a1 = g_isd[s1], a2 = g_isd[s2], a3 = g_isd[s3];
        uint4 x0 = *(const uint4*)(g_xp + (size_t)s0 * IN_F + c * 8);
        uint4 x1 = *(const uint4*)(g_xp + (size_t)s1 * IN_F + c * 8);
        uint4 x2 = *(const uint4*)(g_xp + (size_t)s2 * IN_F + c * 8);
        uint4 x3 = *(const uint4*)(g_xp + (size_t)s3 * IN_F + c * 8);
        float w0[KK], w1[KK], w2v[KK], w3[KK];
#pragma unroll
        for (int k = 0; k < KK; ++k) {
            float d0;
            d0 = a0 - mu0[k]; w0[k]  = __expf(w20[k] * d0 * d0 + t1[k]);
            d0 = a1 - mu0[k]; w1[k]  = __expf(w20[k] * d0 * d0 + t1[k]);
            d0 = a2 - mu0[k]; w2v[k] = __expf(w20[k] * d0 * d0 + t1[k]);
            d0 = a3 - mu0[k]; w3[k]  = __expf(w20[k] * d0 * d0 + t1[k]);
        }
        float f0[8] = {bflo(x0.x), bfhi(x0.x), bflo(x0.y), bfhi(x0.y),
                       bflo(x0.z), bfhi(x0.z), bflo(x0.w), bfhi(x0.w)};
        float f1[8] = {bflo(x1.x), bfhi(x1.x), bflo(x1.y), bfhi(x1.y),
                       bflo(x1.z), bfhi(x1.z), bflo(x1.w), bfhi(x1.w)};
        float f2[8] = {bflo(x2.x), bfhi(x2.x), bflo(x2.y), bfhi(x2.y),
                       bflo(x2.z), bfhi(x2.z), bflo(x2.w), bfhi(x2.w)};
        float f3[8] = {bflo(x3.x), bfhi(x3.x), bflo(x3.y), bfhi(x3.y),
                       bflo(x3.z), bfhi(x3.z), bflo(x3.w), bfhi(x3.w)};
#pragma unroll
        for (int k = 0; k < KK; ++k)
#pragma unroll
            for (int i = 0; i < 8; ++i)
                y[k][i] += w0[k] * f0[i] + w1[k] * f1[i] + w2v[k] * f2[i] + w3[k] * f3[i];
    }
    for (; j < end; ++j) {
        int s0 = g_srcs[j];
        float a0 = g_isd[s0];
        uint4 x0 = *(const uint4*)(g_xp + (size_t)s0 * IN_F + c * 8);
        float w0[KK];
#pragma unroll
        for (int k = 0; k < KK; ++k) {
            float d0 = a0 - mu0[k];
            w0[k] = __expf(w20[k] * d0 * d0 + t1[k]);
        }
        float f0[8] = {bflo(x0.x), bfhi(x0.x), bflo(x0.y), bfhi(x0.y),
                       bflo(x0.z), bfhi(x0.z), bflo(x0.w), bfhi(x0.w)};
#pragma unroll
        for (int k = 0; k < KK; ++k)
#pragma unroll
            for (int i = 0; i < 8; ++i) y[k][i] += w0[k] * f0[i];
    }

    float inv = 1.0f / ((cdeg > 0) ? (float)cdeg : 1.0f);
    int row = wv * 8 + grp;
#pragma unroll
    for (int k = 0; k < KK; ++k) {
        uint4 v;
        v.x = pk(y[k][0] * inv, y[k][1] * inv);
        v.y = pk(y[k][2] * inv, y[k][3] * inv);
        v.z = pk(y[k][4] * inv, y[k][5] * inv);
        v.w = pk(y[k][6] * inv, y[k][7] * inv);
        *(uint4*)&yt[row][k * 64 + c * 8] = v;
    }
    *(uint4*)&yt[row][256 + c * 8] = *(const uint4*)(g_xp + (size_t)n * IN_F + c * 8);
    __syncthreads();

    // ---- MFMA phase ----
    int m = L & 15, q = L >> 4;
    int o = wv * 16 + m;
    float bv = bias[o];
#pragma unroll
    for (int T = 0; T < 2; ++T) {
        float4v acc = {0.f, 0.f, 0.f, 0.f};
#pragma unroll
        for (int s = 0; s < 10; ++s) {
            short8 a = *(const short8*)&yt[T * 16 + m][s * 32 + q * 8];
            short8 b = *(const short8*)&g_gt[(size_t)o * KY + s * 32 + q * 8];
            acc = __builtin_amdgcn_mfma_f32_16x16x32_bf16(a, b, acc, 0, 0, 0);
        }
#pragma unroll
        for (int r = 0; r < 4; ++r) {
            int node = n0 + T * 16 + q * 4 + r;
            out[(size_t)node * OUT_F + o] = acc[r] + bv;
        }
    }
}

extern "C" void kernel_launch(void* const* d_in, const int* in_sizes, int n_in,
                              void* d_out, int out_size, void* d_ws, size_t ws_size,
                              hipStream_t stream) {
    const float* x     = (const float*)d_in[0];
    const int*   ei    = (const int*)d_in[1];     // int64 in reference -> int32 from harness
    const float* g     = (const float*)d_in[2];
    const float* mu    = (const float*)d_in[3];
    const float* sigma = (const float*)d_in[4];
    const float* rw    = (const float*)d_in[5];
    const float* bias  = (const float*)d_in[6];
    float* out = (float*)d_out;

    const int* src = ei;            // [2,E] row-major
    const int* dst = ei + N_EDGES;

    prep_kernel<<<(N_NODES * 32 + 255) / 256, 256, 0, stream>>>(x, g, rw);
    binA1_kernel<<<(N_EDGES + CHUNK - 1) / CHUNK, 256, 0, stream>>>(src, dst);
    bscan_kernel<<<1, 512, 0, stream>>>(sigma);
    binA2_kernel<<<NBUCK, 256, 0, stream>>>();
    fused_kernel<<<N_NODES / 32, 256, 0, stream>>>(mu, bias, out);
}

// Round 12
// 203.687 us; speedup vs baseline: 1.3697x; 1.3697x over previous
//
#include <hip/hip_runtime.h>
#include <math.h>

#define N_NODES 100000
#define N_EDGES 1600000
#define IN_F 64
#define OUT_F 64
#define KK 4
#define KY 320               // 256 (k*64+i) + 64 (x concat for root_w)
#define EPS 1e-15f
#define NBUCK 391            // ceil(100000/256) coarse buckets (dst>>8)
#define CHUNK 4096           // edges per binA1 block
#define BSTRIDE 5120         // padded bucket region stride (mean 4092, sigma 64)

typedef __attribute__((ext_vector_type(8))) short short8;    // 8 x bf16 (4 VGPRs)
typedef __attribute__((ext_vector_type(4))) float float4v;   // MFMA acc

// ---- module-global scratch ----
__device__ int            g_bcur[NBUCK];                     // bucket counts (after binA1)
__device__ unsigned int   g_binned[NBUCK * BSTRIDE];         // (src<<8)|dst_local, bucket-major, 8 MB
__device__ int            g_off[N_NODES + 1];                // final CSR offsets
__device__ float          g_isd[N_NODES];
__device__ float          g_w2[KK * 2];                      // -0.5/(eps+sigma^2)
__device__ unsigned short g_xp[(size_t)N_NODES * IN_F];      // bf16 x, 12.8 MB (gather operand)
__device__ int            g_srcs[N_EDGES];                   // src per edge, dst-CSR order
__device__ unsigned short g_gt[OUT_F * KY];                  // G'^T [o][kk] bf16, 40 KB

static __device__ __forceinline__ unsigned short f2bf(float f) {
    unsigned int u = __float_as_uint(f);
    unsigned int r = u + 0x7fffu + ((u >> 16) & 1u);   // RNE
    return (unsigned short)(r >> 16);
}
static __device__ __forceinline__ float bflo(unsigned int u) { return __uint_as_float(u << 16); }
static __device__ __forceinline__ float bfhi(unsigned int u) { return __uint_as_float(u & 0xffff0000u); }
static __device__ __forceinline__ unsigned int pk(float a, float b) {
    return (unsigned int)f2bf(a) | ((unsigned int)f2bf(b) << 16);
}

// ---------------- K1: prep = zero(bcur) + xpack + packg + w2 ----------------
__global__ void prep_kernel(const float* __restrict__ x, const float* __restrict__ g,
                            const float* __restrict__ rw, const float* __restrict__ sigma) {
    int t = blockIdx.x * blockDim.x + threadIdx.x;
    if (t < N_NODES * (IN_F / 2)) {                  // xpack: bf16 pairs
        float a = x[2 * t], b = x[2 * t + 1];
        ((unsigned int*)g_xp)[t] = pk(a, b);
    }
    if (t < NBUCK) g_bcur[t] = 0;
    if (t < KK * 2) {
        float s = sigma[t];
        g_w2[t] = -0.5f / (EPS + s * s);
    }
    if (t < OUT_F * KY) {                            // packg
        int o = t / KY, kk = t % KY;
        float v;
        if (kk < 256) {
            int k = kk >> 6, i = kk & 63;
            v = g[i * 256 + k * 64 + o];
        } else {
            v = rw[(kk - 256) * 64 + o];
        }
        g_gt[o * KY + kk] = f2bf(v);
    }
}

// ---------------- K2: binA1 — LDS-grouped coarse bucket sort ----------------
// (R11 lesson: launch_bounds stays at (256,4) — raising min-waves/EU spills.)
__global__ __launch_bounds__(256, 4) void binA1_kernel(const int* __restrict__ src,
                                                       const int* __restrict__ dst) {
    __shared__ unsigned int   s_ent[CHUNK];          // 16 KB entries, bucket-grouped
    __shared__ unsigned short s_bkt[CHUNK];          // 8 KB bucket id per slot
    __shared__ int s_hist[NBUCK];
    __shared__ int s_off[448];                       // exclusive scan (7*64 >= NBUCK)
    __shared__ int s_gbase[NBUCK];
    __shared__ int s_cur[NBUCK];
    int t = threadIdx.x;
    int e0 = blockIdx.x * CHUNK;
    int nvalid = N_EDGES - e0; if (nvalid > CHUNK) nvalid = CHUNK;

    int myb[16];
    unsigned int mye[16];
#pragma unroll
    for (int r = 0; r < 16; ++r) {
        int e = e0 + r * 256 + t;
        if (e < N_EDGES) {
            int s = src[e], d = dst[e];
            myb[r] = d >> 8;
            mye[r] = ((unsigned int)s << 8) | (unsigned int)(d & 255);
        } else myb[r] = -1;
    }
    for (int i = t; i < NBUCK; i += 256) { s_hist[i] = 0; s_cur[i] = 0; }
    __syncthreads();
#pragma unroll
    for (int r = 0; r < 16; ++r)
        if (myb[r] >= 0) atomicAdd(&s_hist[myb[r]], 1);
    __syncthreads();
    // exclusive scan of s_hist -> s_off (wave 0, shuffle-scan with carry)
    if (t < 64) {
        int carry = 0;
        for (int seg = 0; seg < 7; ++seg) {
            int idx = seg * 64 + t;
            int v = (idx < NBUCK) ? s_hist[idx] : 0;
            int orig = v;
#pragma unroll
            for (int d = 1; d < 64; d <<= 1) {
                int u = __shfl_up(v, d);
                if (t >= d) v += u;
            }
            s_off[idx] = carry + v - orig;
            carry += __shfl(v, 63);
        }
    }
    __syncthreads();
    // reserve global runs
    for (int i = t; i < NBUCK; i += 256) {
        int c = s_hist[i];
        s_gbase[i] = (c > 0) ? atomicAdd(&g_bcur[i], c) : 0;
    }
    __syncthreads();
    // place into LDS, bucket-grouped
#pragma unroll
    for (int r = 0; r < 16; ++r) {
        int b = myb[r];
        if (b >= 0) {
            int slot = s_off[b] + atomicAdd(&s_cur[b], 1);
            s_ent[slot] = mye[r];
            s_bkt[slot] = (unsigned short)b;
        }
    }
    __syncthreads();
    // flush coalesced runs
    for (int slot = t; slot < nvalid; slot += 256) {
        int b = s_bkt[slot];
        int pos = b * BSTRIDE + s_gbase[b] + (slot - s_off[b]);
        g_binned[pos] = s_ent[slot];
    }
}

// ---------------- K3: binA2 — per-bucket counting sort to exact CSR + g_off + isd ----------------
// Computes its own CSR base (prefix over the 391-entry L2-hot g_bcur) -> bscan launch deleted.
__global__ __launch_bounds__(256, 4) void binA2_kernel() {
    __shared__ int s_hist[256], s_off[256], s_cur[256];
    __shared__ int s_red[4];
    int b = blockIdx.x;
    int t = threadIdx.x;
    int cnt = g_bcur[b];
    // gbase = sum of bucket counts below b (<=391 ints, L2-resident)
    int part = 0;
    for (int i = t; i < b; i += 256) part += g_bcur[i];
#pragma unroll
    for (int d = 32; d >= 1; d >>= 1) part += __shfl_down(part, d);
    if ((t & 63) == 0) s_red[t >> 6] = part;
    s_hist[t] = 0; s_cur[t] = 0;
    __syncthreads();
    int gbase = s_red[0] + s_red[1] + s_red[2] + s_red[3];
    int n0 = b * 256;
    const unsigned int* ent = g_binned + (size_t)b * BSTRIDE;
    for (int i = t; i < cnt; i += 256) atomicAdd(&s_hist[ent[i] & 255u], 1);
    __syncthreads();
    // exclusive scan over 256 (wave 0)
    if (t < 64) {
        int carry = 0;
        for (int seg = 0; seg < 4; ++seg) {
            int idx = seg * 64 + t;
            int v = s_hist[idx];
            int orig = v;
#pragma unroll
            for (int d = 1; d < 64; d <<= 1) {
                int u = __shfl_up(v, d);
                if (t >= d) v += u;
            }
            s_off[idx] = carry + v - orig;
            carry += __shfl(v, 63);
        }
    }
    __syncthreads();
    int n = n0 + t;
    if (n < N_NODES) {
        g_off[n] = gbase + s_off[t];
        int c = s_hist[t];
        g_isd[n] = (c > 0) ? rsqrtf((float)c) : 0.0f;
    }
    if (b == NBUCK - 1 && t == 0) g_off[N_NODES] = N_EDGES;
    __syncthreads();
    for (int i = t; i < cnt; i += 256) {
        unsigned int e = ent[i];
        int dl = e & 255u;
        int pos = gbase + s_off[dl] + atomicAdd(&s_cur[dl], 1);
        g_srcs[pos] = (int)(e >> 8);
    }
}

// ---------------- K4: fused aggregate (w recomputed on the fly) + MFMA epilogue ----------------
// launch_bounds (256,4): known-good (74.7 us, VGPR=64). (256,6) spilled: VGPR 64->40,
// WRITE 37->217 MB scratch traffic, 2x slower (R11). Do not raise.
__global__ __launch_bounds__(256, 4) void fused_kernel(const float* __restrict__ mu,
                                                       const float* __restrict__ bias,
                                                       float* __restrict__ out) {
    __shared__ unsigned short yt[32][328];
    int t = threadIdx.x;
    int wv = t >> 6, L = t & 63;
    int grp = L >> 3, c = L & 7;
    int n0 = blockIdx.x * 32;
    int n = n0 + wv * 8 + grp;

    int off = g_off[n], end = g_off[n + 1];
    int cdeg = end - off;
    float mu0[KK], w20[KK], t1[KK];
    {
        float a1 = (cdeg > 0) ? rsqrtf((float)cdeg) : 0.0f;
#pragma unroll
        for (int k = 0; k < KK; ++k) {
            mu0[k] = mu[k * 2 + 0];
            w20[k] = g_w2[k * 2 + 0];
            float d1 = a1 - mu[k * 2 + 1];
            t1[k] = g_w2[k * 2 + 1] * d1 * d1;
        }
    }

    float y[KK][8];
#pragma unroll
    for (int k = 0; k < KK; ++k)
#pragma unroll
        for (int i = 0; i < 8; ++i) y[k][i] = 0.0f;

    int j = off;
    for (; j + 3 < end; j += 4) {            // 4 edges in flight
        int s0 = g_srcs[j], s1 = g_srcs[j + 1], s2 = g_srcs[j + 2], s3 = g_srcs[j + 3];
        float a0 = g_isd[s0], a1 = g_isd[s1], a2 = g_isd[s2], a3 = g_isd[s3];
        uint4 x0 = *(const uint4*)(g_xp + (size_t)s0 * IN_F + c * 8);
        uint4 x1 = *(const uint4*)(g_xp + (size_t)s1 * IN_F + c * 8);
        uint4 x2 = *(const uint4*)(g_xp + (size_t)s2 * IN_F + c * 8);
        uint4 x3 = *(const uint4*)(g_xp + (size_t)s3 * IN_F + c * 8);
        float w0[KK], w1[KK], w2v[KK], w3[KK];
#pragma unroll
        for (int k = 0; k < KK; ++k) {
            float d0;
            d0 = a0 - mu0[k]; w0[k]  = __expf(w20[k] * d0 * d0 + t1[k]);
            d0 = a1 - mu0[k]; w1[k]  = __expf(w20[k] * d0 * d0 + t1[k]);
            d0 = a2 - mu0[k]; w2v[k] = __expf(w20[k] * d0 * d0 + t1[k]);
            d0 = a3 - mu0[k]; w3[k]  = __expf(w20[k] * d0 * d0 + t1[k]);
        }
        float f0[8] = {bflo(x0.x), bfhi(x0.x), bflo(x0.y), bfhi(x0.y),
                       bflo(x0.z), bfhi(x0.z), bflo(x0.w), bfhi(x0.w)};
        float f1[8] = {bflo(x1.x), bfhi(x1.x), bflo(x1.y), bfhi(x1.y),
                       bflo(x1.z), bfhi(x1.z), bflo(x1.w), bfhi(x1.w)};
        float f2[8] = {bflo(x2.x), bfhi(x2.x), bflo(x2.y), bfhi(x2.y),
                       bflo(x2.z), bfhi(x2.z), bflo(x2.w), bfhi(x2.w)};
        float f3[8] = {bflo(x3.x), bfhi(x3.x), bflo(x3.y), bfhi(x3.y),
                       bflo(x3.z), bfhi(x3.z), bflo(x3.w), bfhi(x3.w)};
#pragma unroll
        for (int k = 0; k < KK; ++k)
#pragma unroll
            for (int i = 0; i < 8; ++i)
                y[k][i] += w0[k] * f0[i] + w1[k] * f1[i] + w2v[k] * f2[i] + w3[k] * f3[i];
    }
    for (; j < end; ++j) {
        int s0 = g_srcs[j];
        float a0 = g_isd[s0];
        uint4 x0 = *(const uint4*)(g_xp + (size_t)s0 * IN_F + c * 8);
        float w0[KK];
#pragma unroll
        for (int k = 0; k < KK; ++k) {
            float d0 = a0 - mu0[k];
            w0[k] = __expf(w20[k] * d0 * d0 + t1[k]);
        }
        float f0[8] = {bflo(x0.x), bfhi(x0.x), bflo(x0.y), bfhi(x0.y),
                       bflo(x0.z), bfhi(x0.z), bflo(x0.w), bfhi(x0.w)};
#pragma unroll
        for (int k = 0; k < KK; ++k)
#pragma unroll
            for (int i = 0; i < 8; ++i) y[k][i] += w0[k] * f0[i];
    }

    float inv = 1.0f / ((cdeg > 0) ? (float)cdeg : 1.0f);
    int row = wv * 8 + grp;
#pragma unroll
    for (int k = 0; k < KK; ++k) {
        uint4 v;
        v.x = pk(y[k][0] * inv, y[k][1] * inv);
        v.y = pk(y[k][2] * inv, y[k][3] * inv);
        v.z = pk(y[k][4] * inv, y[k][5] * inv);
        v.w = pk(y[k][6] * inv, y[k][7] * inv);
        *(uint4*)&yt[row][k * 64 + c * 8] = v;
    }
    *(uint4*)&yt[row][256 + c * 8] = *(const uint4*)(g_xp + (size_t)n * IN_F + c * 8);
    __syncthreads();

    // ---- MFMA phase ----
    int m = L & 15, q = L >> 4;
    int o = wv * 16 + m;
    float bv = bias[o];
#pragma unroll
    for (int T = 0; T < 2; ++T) {
        float4v acc = {0.f, 0.f, 0.f, 0.f};
#pragma unroll
        for (int s = 0; s < 10; ++s) {
            short8 a = *(const short8*)&yt[T * 16 + m][s * 32 + q * 8];
            short8 b = *(const short8*)&g_gt[(size_t)o * KY + s * 32 + q * 8];
            acc = __builtin_amdgcn_mfma_f32_16x16x32_bf16(a, b, acc, 0, 0, 0);
        }
#pragma unroll
        for (int r = 0; r < 4; ++r) {
            int node = n0 + T * 16 + q * 4 + r;
            out[(size_t)node * OUT_F + o] = acc[r] + bv;
        }
    }
}

extern "C" void kernel_launch(void* const* d_in, const int* in_sizes, int n_in,
                              void* d_out, int out_size, void* d_ws, size_t ws_size,
                              hipStream_t stream) {
    const float* x     = (const float*)d_in[0];
    const int*   ei    = (const int*)d_in[1];     // int64 in reference -> int32 from harness
    const float* g     = (const float*)d_in[2];
    const float* mu    = (const float*)d_in[3];
    const float* sigma = (const float*)d_in[4];
    const float* rw    = (const float*)d_in[5];
    const float* bias  = (const float*)d_in[6];
    float* out = (float*)d_out;

    const int* src = ei;            // [2,E] row-major
    const int* dst = ei + N_EDGES;

    prep_kernel<<<(N_NODES * 32 + 255) / 256, 256, 0, stream>>>(x, g, rw, sigma);
    binA1_kernel<<<(N_EDGES + CHUNK - 1) / CHUNK, 256, 0, stream>>>(src, dst);
    binA2_kernel<<<NBUCK, 256, 0, stream>>>();
    fused_kernel<<<N_NODES / 32, 256, 0, stream>>>(mu, bias, out);
}